// Round 14
// baseline (434.567 us; speedup 1.0000x reference)
//
#include <hip/hip_runtime.h>
#include <hip/hip_bf16.h>
#include <cstdint>
#include <cstddef>

#define N_NODES 8192
#define DIN 512
#define DOUT 256
#define CAP 512   // max edges/row buffered; Binom(8192,0.004): mean 32.8, sd 5.7
#define GEMM_BLOCKS 512

typedef short bf16x8 __attribute__((ext_vector_type(8)));
typedef float f32x4 __attribute__((ext_vector_type(4)));
typedef unsigned int u32x4 __attribute__((ext_vector_type(4)));

__device__ __forceinline__ float bf2f(unsigned short u) {
    union { unsigned int ui; float f; } v; v.ui = ((unsigned int)u) << 16; return v.f;
}
__device__ __forceinline__ unsigned short f2bf(float f) {
    union { float f; unsigned int u; } v; v.f = f;
    unsigned int u = v.u;
    return (unsigned short)((u + 0x7fffu + ((u >> 16) & 1u)) >> 16);  // RNE
}
__device__ __forceinline__ float elu1(float v) { return v > 0.f ? v : (expf(v) - 1.f); }

// -------- prep 1: u1 = W1@a1w, u2 = W1@a2w (512 each); c = {b1.a1w+a1b, b1.a2w+a2b} --------
__global__ __launch_bounds__(256) void u12_kernel(
    const float* __restrict__ W1,
    const float* __restrict__ b1,
    const float* __restrict__ a1w, const float* __restrict__ a1b,
    const float* __restrict__ a2w, const float* __restrict__ a2b,
    float* __restrict__ u1, float* __restrict__ u2, float* __restrict__ cc)
{
    const int tid = threadIdx.x;
    if (blockIdx.x < 2) {
        const float* av = (blockIdx.x == 0) ? a1w : a2w;
        float* uv = (blockIdx.x == 0) ? u1 : u2;
        for (int k = tid; k < DIN; k += 256) {
            const float* wrow = W1 + (size_t)k * DOUT;
            float s = 0.f;
            for (int n = 0; n < DOUT; ++n) s += wrow[n] * av[n];
            uv[k] = s;
        }
    } else {
        __shared__ float red[256];
        red[tid] = b1[tid] * a1w[tid]; __syncthreads();
        for (int s = 128; s > 0; s >>= 1) { if (tid < s) red[tid] += red[tid + s]; __syncthreads(); }
        if (tid == 0) cc[0] = red[0] + a1b[0];
        __syncthreads();
        red[tid] = b1[tid] * a2w[tid]; __syncthreads();
        for (int s = 128; s > 0; s >>= 1) { if (tid < s) red[tid] += red[tid + s]; __syncthreads(); }
        if (tid == 0) cc[1] = red[0] + a2b[0];
    }
}

// -------- prep 2: wb[n][k] = bf16(W1[k][n])  [256,512] --------
__global__ __launch_bounds__(256) void convw_kernel(
    const float* __restrict__ W1, unsigned short* __restrict__ wb)
{
    const int n = blockIdx.x;
    const int k = threadIdx.x * 2;
    unsigned short a = f2bf(W1[(size_t)k * DOUT + n]);
    unsigned short b = f2bf(W1[(size_t)(k + 1) * DOUT + n]);
    *(unsigned int*)(wb + (size_t)n * DIN + k) = (unsigned int)a | ((unsigned int)b << 16);
}

// -------- kernel: g1/g2 straight from x (wave per row; fp32-exact) --------
__global__ __launch_bounds__(256) void g12x_kernel(
    const float* __restrict__ x,
    const float* __restrict__ u1, const float* __restrict__ u2,
    const float* __restrict__ cc,
    float* __restrict__ g1, float* __restrict__ g2)
{
    const int tid = threadIdx.x;
    const int wave = tid >> 6, lane = tid & 63;
    const int i = blockIdx.x * 4 + wave;
    const int k0 = lane * 8;
    const float* xr = x + (size_t)i * DIN + k0;
    float4 f0 = *(const float4*)xr;
    float4 f1 = *(const float4*)(xr + 4);
    float4 p0 = *(const float4*)(u1 + k0);
    float4 p1 = *(const float4*)(u1 + k0 + 4);
    float4 q0 = *(const float4*)(u2 + k0);
    float4 q1 = *(const float4*)(u2 + k0 + 4);
    float e0 = elu1(f0.x), e1 = elu1(f0.y), e2 = elu1(f0.z), e3 = elu1(f0.w);
    float e4 = elu1(f1.x), e5 = elu1(f1.y), e6 = elu1(f1.z), e7 = elu1(f1.w);
    float s1 = e0*p0.x + e1*p0.y + e2*p0.z + e3*p0.w + e4*p1.x + e5*p1.y + e6*p1.z + e7*p1.w;
    float s2 = e0*q0.x + e1*q0.y + e2*q0.z + e3*q0.w + e4*q1.x + e5*q1.y + e6*q1.z + e7*q1.w;
    #pragma unroll
    for (int off = 32; off > 0; off >>= 1) {
        s1 += __shfl_xor(s1, off, 64);
        s2 += __shfl_xor(s2, off, 64);
    }
    if (lane == 0) {
        g1[i] = s1 + cc[0];
        g2[i] = s2 + cc[1];
    }
}

// -------- fat kernel: blocks [0,512) = GEMM h; blocks [512,8704) = adj scan+softmax --------
// GEMM and scan have no data dependency (g1/g2 come from x), so they co-run on the CUs;
// the ~25us GEMM hides entirely under the ~100us BW-bound scan.
__global__ __launch_bounds__(256) void fat_kernel(
    const float* __restrict__ x, const unsigned short* __restrict__ wb,
    const float* __restrict__ b1, unsigned short* __restrict__ h,
    const float* __restrict__ adj,
    const float* __restrict__ g1, const float* __restrict__ g2,
    int* __restrict__ jl, float* __restrict__ pl, int* __restrict__ cnts)
{
    const int tid = threadIdx.x;
    if (blockIdx.x < GEMM_BLOCKS) {
        // ---- GEMM tile M=16 x N=256 (R12 body, verified) ----
        const int wave = tid >> 6, lane = tid & 63;
        const int quad = lane >> 4, r16 = lane & 15;
        const int m0 = blockIdx.x * 16;
        const int n0 = wave * 64;
        f32x4 acc[4] = {{0.f,0.f,0.f,0.f},{0.f,0.f,0.f,0.f},{0.f,0.f,0.f,0.f},{0.f,0.f,0.f,0.f}};
        const float* xrow = x + (size_t)(m0 + r16) * DIN;
        for (int k0 = 0; k0 < DIN; k0 += 32) {
            const int kb = k0 + quad * 8;
            float4 f0 = *(const float4*)(xrow + kb);
            float4 f1 = *(const float4*)(xrow + kb + 4);
            bf16x8 A;
            A[0] = (short)f2bf(elu1(f0.x)); A[1] = (short)f2bf(elu1(f0.y));
            A[2] = (short)f2bf(elu1(f0.z)); A[3] = (short)f2bf(elu1(f0.w));
            A[4] = (short)f2bf(elu1(f1.x)); A[5] = (short)f2bf(elu1(f1.y));
            A[6] = (short)f2bf(elu1(f1.z)); A[7] = (short)f2bf(elu1(f1.w));
            bf16x8 B[4];
            #pragma unroll
            for (int s = 0; s < 4; ++s)
                B[s] = *(const bf16x8*)(wb + (size_t)(n0 + s * 16 + r16) * DIN + kb);
            #pragma unroll
            for (int ni = 0; ni < 4; ++ni)
                acc[ni] = __builtin_amdgcn_mfma_f32_16x16x32_bf16(A, B[ni], acc[ni], 0, 0, 0);
        }
        #pragma unroll
        for (int ni = 0; ni < 4; ++ni) {
            const int col = n0 + ni * 16 + r16;
            const float bias = b1[col];
            #pragma unroll
            for (int rr = 0; rr < 4; ++rr)
                h[(size_t)(m0 + quad * 4 + rr) * DOUT + col] = f2bf(acc[ni][rr] + bias);
        }
        return;
    }

    // ---- adj scan + softmax for row i (R6 body, verified; NT loads) ----
    __shared__ int   eidx[CAP];
    __shared__ float ev[CAP];
    __shared__ float red[256];
    __shared__ int   cnt;

    const int i = blockIdx.x - GEMM_BLOCKS;
    if (tid == 0) cnt = 0;
    __syncthreads();

    const float g2i = g2[i];
    const float* arow = adj + (size_t)i * N_NODES;

    u32x4 raws[8];
    #pragma unroll
    for (int c = 0; c < 8; ++c)
        raws[c] = __builtin_nontemporal_load((const u32x4*)(arow + c * 1024 + tid * 4));

    #pragma unroll
    for (int c = 0; c < 8; ++c) {
        u32x4 raw = raws[c];
        if (raw.x | raw.y | raw.z | raw.w) {
            unsigned int wv[4] = {raw.x, raw.y, raw.z, raw.w};
            #pragma unroll
            for (int q = 0; q < 4; ++q) {
                if (wv[q]) {
                    int j = c * 1024 + tid * 4 + q;
                    union { unsigned int u; float f; } av; av.u = wv[q];
                    float s = av.f * (g2i + g1[j]);    // adj value is exactly 1.0
                    float lr = s > 0.f ? s : 0.2f * s; // leaky_relu(0.2)
                    int pos = atomicAdd(&cnt, 1);
                    if (pos < CAP) { eidx[pos] = j; ev[pos] = lr; }
                }
            }
        }
    }
    __syncthreads();
    const int K = cnt < CAP ? cnt : CAP;
    if (tid == 0) cnts[i] = K;
    if (K == 0) return;

    float mloc = -1e30f;
    for (int k = tid; k < K; k += 256) mloc = fmaxf(mloc, ev[k]);
    red[tid] = mloc; __syncthreads();
    for (int s = 128; s > 0; s >>= 1) {
        if (tid < s) red[tid] = fmaxf(red[tid], red[tid + s]);
        __syncthreads();
    }
    const float m = red[0];
    __syncthreads();

    float sloc = 0.f;
    for (int k = tid; k < K; k += 256) { float p = expf(ev[k] - m); ev[k] = p; sloc += p; }
    red[tid] = sloc; __syncthreads();
    for (int s = 128; s > 0; s >>= 1) {
        if (tid < s) red[tid] += red[tid + s];
        __syncthreads();
    }
    const float inv = 1.f / red[0];

    for (int k = tid; k < K; k += 256) {
        jl[(size_t)i * CAP + k] = eidx[k];
        pl[(size_t)i * CAP + k] = ev[k] * inv;    // pre-normalized weight
    }
}

// -------- gather: out[i,:] = sum_k w_k * h[j_k,:]  (block per row) --------
__global__ __launch_bounds__(256) void gather_kernel(
    const int* __restrict__ jl, const float* __restrict__ pl,
    const int* __restrict__ cnts, const unsigned short* __restrict__ h,
    float* __restrict__ out)
{
    __shared__ int   jbuf[CAP];
    __shared__ float pbuf[CAP];

    const int tid = threadIdx.x;
    const int i = blockIdx.x;
    int K = cnts[i]; if (K > CAP) K = CAP;

    if (K == 0) {
        // softmax over all -9e15 -> uniform 1/N -> column mean of h
        float acc = 0.f;
        for (int j = 0; j < N_NODES; ++j) acc += bf2f(h[(size_t)j * DOUT + tid]);
        out[(size_t)i * DOUT + tid] = acc / (float)N_NODES;
        return;
    }

    for (int k = tid; k < K; k += 256) {
        jbuf[k] = jl[(size_t)i * CAP + k];
        pbuf[k] = pl[(size_t)i * CAP + k];
    }
    __syncthreads();

    float acc = 0.f;
    int k = 0;
    for (; k + 4 <= K; k += 4) {
        float p0 = pbuf[k],   p1 = pbuf[k+1], p2 = pbuf[k+2], p3 = pbuf[k+3];
        int   j0 = jbuf[k],   j1 = jbuf[k+1], j2 = jbuf[k+2], j3 = jbuf[k+3];
        float v0 = bf2f(h[(size_t)j0 * DOUT + tid]);
        float v1 = bf2f(h[(size_t)j1 * DOUT + tid]);
        float v2 = bf2f(h[(size_t)j2 * DOUT + tid]);
        float v3 = bf2f(h[(size_t)j3 * DOUT + tid]);
        acc += p0 * v0 + p1 * v1 + p2 * v2 + p3 * v3;
    }
    for (; k < K; ++k) acc += pbuf[k] * bf2f(h[(size_t)jbuf[k] * DOUT + tid]);
    out[(size_t)i * DOUT + tid] = acc;
}

extern "C" void kernel_launch(void* const* d_in, const int* in_sizes, int n_in,
                              void* d_out, int out_size, void* d_ws, size_t ws_size,
                              hipStream_t stream) {
    const float* x   = (const float*)d_in[0];  // [8192,512] fp32
    const float* adj = (const float*)d_in[1];  // [8192,8192] fp32
    const float* W1  = (const float*)d_in[2];  // [512,256] fp32
    const float* b1  = (const float*)d_in[3];  // [256] fp32
    const float* a1w = (const float*)d_in[4];  // [256] fp32
    const float* a1b = (const float*)d_in[5];  // [1] fp32
    const float* a2w = (const float*)d_in[6];  // [256] fp32
    const float* a2b = (const float*)d_in[7];  // [1] fp32

    // ws: g1 | g2 | u1 | u2 | cc | h bf16 | wb bf16 | jl int | pl f32 | cnts  (~36.8 MB)
    char* w = (char*)d_ws;
    float* g1 = (float*)w;                     w += (size_t)N_NODES * 4;
    float* g2 = (float*)w;                     w += (size_t)N_NODES * 4;
    float* u1 = (float*)w;                     w += (size_t)DIN * 4;
    float* u2 = (float*)w;                     w += (size_t)DIN * 4;
    float* cc = (float*)w;                     w += 64;
    unsigned short* h  = (unsigned short*)w;   w += (size_t)N_NODES * DOUT * 2;
    unsigned short* wb = (unsigned short*)w;   w += (size_t)DOUT * DIN * 2;
    int* jl = (int*)w;                         w += (size_t)N_NODES * CAP * 4;
    float* pl = (float*)w;                     w += (size_t)N_NODES * CAP * 4;
    int* cnts = (int*)w;
    float* out = (float*)d_out;                // [8192,256] fp32

    hipLaunchKernelGGL(u12_kernel,    dim3(3),    dim3(256), 0, stream, W1, b1, a1w, a1b, a2w, a2b, u1, u2, cc);
    hipLaunchKernelGGL(convw_kernel,  dim3(256),  dim3(256), 0, stream, W1, wb);
    hipLaunchKernelGGL(g12x_kernel,   dim3(2048), dim3(256), 0, stream, x, u1, u2, cc, g1, g2);
    hipLaunchKernelGGL(fat_kernel,    dim3(GEMM_BLOCKS + N_NODES), dim3(256), 0, stream,
                       x, wb, b1, h, adj, g1, g2, jl, pl, cnts);
    hipLaunchKernelGGL(gather_kernel, dim3(N_NODES), dim3(256), 0, stream, jl, pl, cnts, h, out);
}

// Round 15
// 404.188 us; speedup vs baseline: 1.0752x; 1.0752x over previous
//
#include <hip/hip_runtime.h>
#include <hip/hip_bf16.h>
#include <cstdint>
#include <cstddef>

#define N_NODES 8192
#define DIN 512
#define DOUT 256
#define CAP 512   // max edges/row buffered; Binom(8192,0.004): mean 32.8, sd 5.7

typedef short bf16x8 __attribute__((ext_vector_type(8)));
typedef float f32x4 __attribute__((ext_vector_type(4)));
typedef unsigned int u32x4 __attribute__((ext_vector_type(4)));

__device__ __forceinline__ float bf2f(unsigned short u) {
    union { unsigned int ui; float f; } v; v.ui = ((unsigned int)u) << 16; return v.f;
}
__device__ __forceinline__ unsigned short f2bf(float f) {
    union { float f; unsigned int u; } v; v.f = f;
    unsigned int u = v.u;
    return (unsigned short)((u + 0x7fffu + ((u >> 16) & 1u)) >> 16);  // RNE
}
__device__ __forceinline__ float elu1(float v) { return v > 0.f ? v : (expf(v) - 1.f); }

// -------- prep: wb[n][k] = bf16(W1[k][n])  [256,512] (k-contiguous per col) --------
__global__ __launch_bounds__(256) void convw_kernel(
    const float* __restrict__ W1, unsigned short* __restrict__ wb)
{
    const int n = blockIdx.x;            // 256
    const int k = threadIdx.x * 2;       // 0..510
    unsigned short a = f2bf(W1[(size_t)k * DOUT + n]);
    unsigned short b = f2bf(W1[(size_t)(k + 1) * DOUT + n]);
    *(unsigned int*)(wb + (size_t)n * DIN + k) = (unsigned int)a | ((unsigned int)b << 16);
}

// -------- kernel 1: h = elu(x) @ wb^T + b1 -> bf16 h --------
// tile M=16 x N=256, grid 512 (2 blocks/CU, 8 waves/CU). A built in-register from
// fp32 x with inline elu (each x row read by exactly one block -> no redundancy);
// B is 16-B contiguous bf16 from wb (L2-resident, 256 KB).
// mfma_f32_16x16x32_bf16: A[m=lane&15][k=quad*8+j], B[k=quad*8+j][n=lane&15],
// D[row=quad*4+r][col=lane&15]
__global__ __launch_bounds__(256) void gemm_h_kernel(
    const float* __restrict__ x, const unsigned short* __restrict__ wb,
    const float* __restrict__ b1, unsigned short* __restrict__ h)
{
    const int tid = threadIdx.x;
    const int wave = tid >> 6, lane = tid & 63;
    const int quad = lane >> 4, r16 = lane & 15;
    const int m0 = blockIdx.x * 16;        // 512 m-blocks
    const int n0 = wave * 64;              // 4 n-subtiles per wave

    f32x4 acc[4] = {{0.f,0.f,0.f,0.f},{0.f,0.f,0.f,0.f},{0.f,0.f,0.f,0.f},{0.f,0.f,0.f,0.f}};
    const float* xrow = x + (size_t)(m0 + r16) * DIN;

    for (int k0 = 0; k0 < DIN; k0 += 32) {
        const int kb = k0 + quad * 8;
        float4 f0 = *(const float4*)(xrow + kb);
        float4 f1 = *(const float4*)(xrow + kb + 4);
        bf16x8 A;
        A[0] = (short)f2bf(elu1(f0.x)); A[1] = (short)f2bf(elu1(f0.y));
        A[2] = (short)f2bf(elu1(f0.z)); A[3] = (short)f2bf(elu1(f0.w));
        A[4] = (short)f2bf(elu1(f1.x)); A[5] = (short)f2bf(elu1(f1.y));
        A[6] = (short)f2bf(elu1(f1.z)); A[7] = (short)f2bf(elu1(f1.w));
        bf16x8 B[4];
        #pragma unroll
        for (int s = 0; s < 4; ++s)
            B[s] = *(const bf16x8*)(wb + (size_t)(n0 + s * 16 + r16) * DIN + kb);
        #pragma unroll
        for (int ni = 0; ni < 4; ++ni)
            acc[ni] = __builtin_amdgcn_mfma_f32_16x16x32_bf16(A, B[ni], acc[ni], 0, 0, 0);
    }
    #pragma unroll
    for (int ni = 0; ni < 4; ++ni) {
        const int col = n0 + ni * 16 + r16;
        const float bias = b1[col];
        #pragma unroll
        for (int rr = 0; rr < 4; ++rr)
            h[(size_t)(m0 + quad * 4 + rr) * DOUT + col] = f2bf(acc[ni][rr] + bias);
    }
}

// -------- kernel 2: g1 = h@a1_w + a1_b, g2 = h@a2_w + a2_b  (wave per row) --------
__global__ __launch_bounds__(256) void g12_kernel(
    const unsigned short* __restrict__ h,
    const float* __restrict__ a1w, const float* __restrict__ a1b,
    const float* __restrict__ a2w, const float* __restrict__ a2b,
    float* __restrict__ g1, float* __restrict__ g2)
{
    const int tid = threadIdx.x;
    const int wave = tid >> 6, lane = tid & 63;
    const int i = blockIdx.x * 4 + wave;
    const int d0 = lane * 4;
    ushort4 hv = *(const ushort4*)(h + (size_t)i * DOUT + d0);
    float4 w1 = *(const float4*)(a1w + d0);
    float4 w2 = *(const float4*)(a2w + d0);
    float h0 = bf2f(hv.x), h1 = bf2f(hv.y), h2 = bf2f(hv.z), h3 = bf2f(hv.w);
    float s1 = h0*w1.x + h1*w1.y + h2*w1.z + h3*w1.w;
    float s2 = h0*w2.x + h1*w2.y + h2*w2.z + h3*w2.w;
    #pragma unroll
    for (int off = 32; off > 0; off >>= 1) {
        s1 += __shfl_xor(s1, off, 64);
        s2 += __shfl_xor(s2, off, 64);
    }
    if (lane == 0) {
        g1[i] = s1 + a1b[0];
        g2[i] = s2 + a2b[0];
    }
}

// -------- kernel 3: per-row masked softmax + aggregation (R6-best, NT loads) --------
__global__ __launch_bounds__(256) void agg_kernel(
    const float* __restrict__ adj, const unsigned short* __restrict__ h,
    const float* __restrict__ g1, const float* __restrict__ g2,
    float* __restrict__ out)
{
    __shared__ int   eidx[CAP];
    __shared__ float ev[CAP];
    __shared__ float red[256];
    __shared__ int   cnt;

    const int tid = threadIdx.x;
    const int i = blockIdx.x;
    if (tid == 0) cnt = 0;
    __syncthreads();

    const float g2i = g2[i];
    const float* arow = adj + (size_t)i * N_NODES;

    // prefetch all 8 streaming loads (nontemporal: adj has zero reuse; A/B'd R6 vs R9: NT -12us)
    u32x4 raws[8];
    #pragma unroll
    for (int c = 0; c < 8; ++c)
        raws[c] = __builtin_nontemporal_load((const u32x4*)(arow + c * 1024 + tid * 4));

    #pragma unroll
    for (int c = 0; c < 8; ++c) {
        u32x4 raw = raws[c];
        if (raw.x | raw.y | raw.z | raw.w) {
            unsigned int wv[4] = {raw.x, raw.y, raw.z, raw.w};
            #pragma unroll
            for (int q = 0; q < 4; ++q) {
                if (wv[q]) {
                    int j = c * 1024 + tid * 4 + q;
                    union { unsigned int u; float f; } av; av.u = wv[q];
                    float s = av.f * (g2i + g1[j]);    // adj value is exactly 1.0
                    float lr = s > 0.f ? s : 0.2f * s; // leaky_relu(0.2)
                    int pos = atomicAdd(&cnt, 1);
                    if (pos < CAP) { eidx[pos] = j; ev[pos] = lr; }
                }
            }
        }
    }
    __syncthreads();
    const int K = cnt < CAP ? cnt : CAP;

    if (K == 0) {
        float acc = 0.f;
        for (int j = 0; j < N_NODES; ++j) acc += bf2f(h[(size_t)j * DOUT + tid]);
        out[(size_t)i * DOUT + tid] = acc / (float)N_NODES;
        return;
    }

    float mloc = -1e30f;
    for (int k = tid; k < K; k += 256) mloc = fmaxf(mloc, ev[k]);
    red[tid] = mloc; __syncthreads();
    for (int s = 128; s > 0; s >>= 1) {
        if (tid < s) red[tid] = fmaxf(red[tid], red[tid + s]);
        __syncthreads();
    }
    const float m = red[0];
    __syncthreads();

    float sloc = 0.f;
    for (int k = tid; k < K; k += 256) { float p = expf(ev[k] - m); ev[k] = p; sloc += p; }
    red[tid] = sloc; __syncthreads();
    for (int s = 128; s > 0; s >>= 1) {
        if (tid < s) red[tid] += red[tid + s];
        __syncthreads();
    }
    const float inv = 1.f / red[0];

    float acc = 0.f;
    int k = 0;
    for (; k + 4 <= K; k += 4) {
        float p0 = ev[k],     p1 = ev[k + 1], p2 = ev[k + 2], p3 = ev[k + 3];
        int   j0 = eidx[k],   j1 = eidx[k+1], j2 = eidx[k+2], j3 = eidx[k+3];
        float v0 = bf2f(h[(size_t)j0 * DOUT + tid]);
        float v1 = bf2f(h[(size_t)j1 * DOUT + tid]);
        float v2 = bf2f(h[(size_t)j2 * DOUT + tid]);
        float v3 = bf2f(h[(size_t)j3 * DOUT + tid]);
        acc += p0 * v0 + p1 * v1 + p2 * v2 + p3 * v3;
    }
    for (; k < K; ++k) acc += ev[k] * bf2f(h[(size_t)eidx[k] * DOUT + tid]);
    out[(size_t)i * DOUT + tid] = acc * inv;
}

extern "C" void kernel_launch(void* const* d_in, const int* in_sizes, int n_in,
                              void* d_out, int out_size, void* d_ws, size_t ws_size,
                              hipStream_t stream) {
    const float* x   = (const float*)d_in[0];  // [8192,512] fp32
    const float* adj = (const float*)d_in[1];  // [8192,8192] fp32
    const float* W1  = (const float*)d_in[2];  // [512,256] fp32
    const float* b1  = (const float*)d_in[3];  // [256] fp32
    const float* a1w = (const float*)d_in[4];  // [256] fp32
    const float* a1b = (const float*)d_in[5];  // [1] fp32
    const float* a2w = (const float*)d_in[6];  // [256] fp32
    const float* a2b = (const float*)d_in[7];  // [1] fp32

    // ws: g1 | g2 | h bf16[8192*256] | wb bf16[256*512]   (~4.5 MB)
    char* w = (char*)d_ws;
    float* g1 = (float*)w;                     w += (size_t)N_NODES * 4;
    float* g2 = (float*)w;                     w += (size_t)N_NODES * 4;
    unsigned short* h  = (unsigned short*)w;   w += (size_t)N_NODES * DOUT * 2;
    unsigned short* wb = (unsigned short*)w;
    float* out = (float*)d_out;                // [8192,256] fp32

    hipLaunchKernelGGL(convw_kernel,  dim3(256),  dim3(256), 0, stream, W1, wb);
    hipLaunchKernelGGL(gemm_h_kernel, dim3(512),  dim3(256), 0, stream, x, wb, b1, h);
    hipLaunchKernelGGL(g12_kernel,    dim3(2048), dim3(256), 0, stream, h, a1w, a1b, a2w, a2b, g1, g2);
    hipLaunchKernelGGL(agg_kernel,    dim3(8192), dim3(256), 0, stream, adj, h, g1, g2, out);
}

// Round 16
// 400.341 us; speedup vs baseline: 1.0855x; 1.0096x over previous
//
#include <hip/hip_runtime.h>
#include <hip/hip_bf16.h>
#include <cstdint>
#include <cstddef>

#define N_NODES 8192
#define DIN 512
#define DOUT 256
#define CAP 512   // max edges/row buffered; Binom(8192,0.004): mean 32.8, sd 5.7

typedef short bf16x8 __attribute__((ext_vector_type(8)));
typedef float f32x4 __attribute__((ext_vector_type(4)));
typedef unsigned int u32x4 __attribute__((ext_vector_type(4)));

__device__ __forceinline__ float bf2f(unsigned short u) {
    union { unsigned int ui; float f; } v; v.ui = ((unsigned int)u) << 16; return v.f;
}
__device__ __forceinline__ unsigned short f2bf(float f) {
    union { float f; unsigned int u; } v; v.f = f;
    unsigned int u = v.u;
    return (unsigned short)((u + 0x7fffu + ((u >> 16) & 1u)) >> 16);  // RNE
}
__device__ __forceinline__ float elu1(float v) { return v > 0.f ? v : (expf(v) - 1.f); }

// -------- prep: wb[n][k] = bf16(W1[k][n])  [256,512] (k-contiguous per col) --------
__global__ __launch_bounds__(256) void convw_kernel(
    const float* __restrict__ W1, unsigned short* __restrict__ wb)
{
    const int n = blockIdx.x;            // 256
    const int k = threadIdx.x * 2;       // 0..510
    unsigned short a = f2bf(W1[(size_t)k * DOUT + n]);
    unsigned short b = f2bf(W1[(size_t)(k + 1) * DOUT + n]);
    *(unsigned int*)(wb + (size_t)n * DIN + k) = (unsigned int)a | ((unsigned int)b << 16);
}

// -------- kernel 1: h = elu(x) @ wb^T + b1 -> bf16 h, WITH fused g1/g2 epilogue --------
// tile M=16 x N=256, grid 512 (2 blocks/CU). Block owns FULL rows of h, so
// g1[i]=h[i,:]@a1w+a1b / g2 likewise are computed in-block: per-lane partials ->
// 16-lane shuffle reduce (within quad) -> LDS cross-wave sum. Saves the g12 kernel.
// mfma_f32_16x16x32_bf16: A[m=lane&15][k=quad*8+j], B[k=quad*8+j][n=lane&15],
// D[row=quad*4+r][col=lane&15]
__global__ __launch_bounds__(256) void gemm_h_kernel(
    const float* __restrict__ x, const unsigned short* __restrict__ wb,
    const float* __restrict__ b1,
    const float* __restrict__ a1w, const float* __restrict__ a1b,
    const float* __restrict__ a2w, const float* __restrict__ a2b,
    unsigned short* __restrict__ h, float* __restrict__ g1, float* __restrict__ g2)
{
    const int tid = threadIdx.x;
    const int wave = tid >> 6, lane = tid & 63;
    const int quad = lane >> 4, r16 = lane & 15;
    const int m0 = blockIdx.x * 16;        // 512 m-blocks
    const int n0 = wave * 64;              // 4 n-subtiles per wave

    f32x4 acc[4] = {{0.f,0.f,0.f,0.f},{0.f,0.f,0.f,0.f},{0.f,0.f,0.f,0.f},{0.f,0.f,0.f,0.f}};
    const float* xrow = x + (size_t)(m0 + r16) * DIN;

    for (int k0 = 0; k0 < DIN; k0 += 32) {
        const int kb = k0 + quad * 8;
        float4 f0 = *(const float4*)(xrow + kb);
        float4 f1 = *(const float4*)(xrow + kb + 4);
        bf16x8 A;
        A[0] = (short)f2bf(elu1(f0.x)); A[1] = (short)f2bf(elu1(f0.y));
        A[2] = (short)f2bf(elu1(f0.z)); A[3] = (short)f2bf(elu1(f0.w));
        A[4] = (short)f2bf(elu1(f1.x)); A[5] = (short)f2bf(elu1(f1.y));
        A[6] = (short)f2bf(elu1(f1.z)); A[7] = (short)f2bf(elu1(f1.w));
        bf16x8 B[4];
        #pragma unroll
        for (int s = 0; s < 4; ++s)
            B[s] = *(const bf16x8*)(wb + (size_t)(n0 + s * 16 + r16) * DIN + kb);
        #pragma unroll
        for (int ni = 0; ni < 4; ++ni)
            acc[ni] = __builtin_amdgcn_mfma_f32_16x16x32_bf16(A, B[ni], acc[ni], 0, 0, 0);
    }

    // epilogue: write h and accumulate per-row dot partials with a1w/a2w
    float p1[4] = {0.f, 0.f, 0.f, 0.f};
    float p2[4] = {0.f, 0.f, 0.f, 0.f};
    #pragma unroll
    for (int ni = 0; ni < 4; ++ni) {
        const int col = n0 + ni * 16 + r16;
        const float bias = b1[col];
        const float w1c = a1w[col], w2c = a2w[col];
        #pragma unroll
        for (int rr = 0; rr < 4; ++rr) {
            float val = acc[ni][rr] + bias;
            h[(size_t)(m0 + quad * 4 + rr) * DOUT + col] = f2bf(val);
            p1[rr] += val * w1c;
            p2[rr] += val * w2c;
        }
    }
    // reduce across the 16 lanes of this quad (xor 1,2,4,8 stays within the quad)
    #pragma unroll
    for (int off = 1; off < 16; off <<= 1) {
        #pragma unroll
        for (int rr = 0; rr < 4; ++rr) {
            p1[rr] += __shfl_xor(p1[rr], off, 64);
            p2[rr] += __shfl_xor(p2[rr], off, 64);
        }
    }
    __shared__ float sg1[16][4];
    __shared__ float sg2[16][4];
    if (r16 == 0) {
        #pragma unroll
        for (int rr = 0; rr < 4; ++rr) {
            sg1[quad * 4 + rr][wave] = p1[rr];
            sg2[quad * 4 + rr][wave] = p2[rr];
        }
    }
    __syncthreads();
    if (tid < 16) {
        float t1 = sg1[tid][0] + sg1[tid][1] + sg1[tid][2] + sg1[tid][3];
        float t2 = sg2[tid][0] + sg2[tid][1] + sg2[tid][2] + sg2[tid][3];
        g1[m0 + tid] = t1 + a1b[0];
        g2[m0 + tid] = t2 + a2b[0];
    }
}

// -------- kernel 2: per-row masked softmax + aggregation (R6-best, NT loads) --------
__global__ __launch_bounds__(256) void agg_kernel(
    const float* __restrict__ adj, const unsigned short* __restrict__ h,
    const float* __restrict__ g1, const float* __restrict__ g2,
    float* __restrict__ out)
{
    __shared__ int   eidx[CAP];
    __shared__ float ev[CAP];
    __shared__ float red[256];
    __shared__ int   cnt;

    const int tid = threadIdx.x;
    const int i = blockIdx.x;
    if (tid == 0) cnt = 0;
    __syncthreads();

    const float g2i = g2[i];
    const float* arow = adj + (size_t)i * N_NODES;

    // prefetch all 8 streaming loads (nontemporal: adj has zero reuse; A/B'd R6 vs R9: NT -12us)
    u32x4 raws[8];
    #pragma unroll
    for (int c = 0; c < 8; ++c)
        raws[c] = __builtin_nontemporal_load((const u32x4*)(arow + c * 1024 + tid * 4));

    #pragma unroll
    for (int c = 0; c < 8; ++c) {
        u32x4 raw = raws[c];
        if (raw.x | raw.y | raw.z | raw.w) {
            unsigned int wv[4] = {raw.x, raw.y, raw.z, raw.w};
            #pragma unroll
            for (int q = 0; q < 4; ++q) {
                if (wv[q]) {
                    int j = c * 1024 + tid * 4 + q;
                    union { unsigned int u; float f; } av; av.u = wv[q];
                    float s = av.f * (g2i + g1[j]);    // adj value is exactly 1.0
                    float lr = s > 0.f ? s : 0.2f * s; // leaky_relu(0.2)
                    int pos = atomicAdd(&cnt, 1);
                    if (pos < CAP) { eidx[pos] = j; ev[pos] = lr; }
                }
            }
        }
    }
    __syncthreads();
    const int K = cnt < CAP ? cnt : CAP;

    if (K == 0) {
        float acc = 0.f;
        for (int j = 0; j < N_NODES; ++j) acc += bf2f(h[(size_t)j * DOUT + tid]);
        out[(size_t)i * DOUT + tid] = acc / (float)N_NODES;
        return;
    }

    float mloc = -1e30f;
    for (int k = tid; k < K; k += 256) mloc = fmaxf(mloc, ev[k]);
    red[tid] = mloc; __syncthreads();
    for (int s = 128; s > 0; s >>= 1) {
        if (tid < s) red[tid] = fmaxf(red[tid], red[tid + s]);
        __syncthreads();
    }
    const float m = red[0];
    __syncthreads();

    float sloc = 0.f;
    for (int k = tid; k < K; k += 256) { float p = expf(ev[k] - m); ev[k] = p; sloc += p; }
    red[tid] = sloc; __syncthreads();
    for (int s = 128; s > 0; s >>= 1) {
        if (tid < s) red[tid] += red[tid + s];
        __syncthreads();
    }
    const float inv = 1.f / red[0];

    float acc = 0.f;
    int k = 0;
    for (; k + 4 <= K; k += 4) {
        float p0 = ev[k],     p1 = ev[k + 1], p2 = ev[k + 2], p3 = ev[k + 3];
        int   j0 = eidx[k],   j1 = eidx[k+1], j2 = eidx[k+2], j3 = eidx[k+3];
        float v0 = bf2f(h[(size_t)j0 * DOUT + tid]);
        float v1 = bf2f(h[(size_t)j1 * DOUT + tid]);
        float v2 = bf2f(h[(size_t)j2 * DOUT + tid]);
        float v3 = bf2f(h[(size_t)j3 * DOUT + tid]);
        acc += p0 * v0 + p1 * v1 + p2 * v2 + p3 * v3;
    }
    for (; k < K; ++k) acc += ev[k] * bf2f(h[(size_t)eidx[k] * DOUT + tid]);
    out[(size_t)i * DOUT + tid] = acc * inv;
}

extern "C" void kernel_launch(void* const* d_in, const int* in_sizes, int n_in,
                              void* d_out, int out_size, void* d_ws, size_t ws_size,
                              hipStream_t stream) {
    const float* x   = (const float*)d_in[0];  // [8192,512] fp32
    const float* adj = (const float*)d_in[1];  // [8192,8192] fp32
    const float* W1  = (const float*)d_in[2];  // [512,256] fp32
    const float* b1  = (const float*)d_in[3];  // [256] fp32
    const float* a1w = (const float*)d_in[4];  // [256] fp32
    const float* a1b = (const float*)d_in[5];  // [1] fp32
    const float* a2w = (const float*)d_in[6];  // [256] fp32
    const float* a2b = (const float*)d_in[7];  // [1] fp32

    // ws: g1 | g2 | h bf16[8192*256] | wb bf16[256*512]   (~4.5 MB)
    char* w = (char*)d_ws;
    float* g1 = (float*)w;                     w += (size_t)N_NODES * 4;
    float* g2 = (float*)w;                     w += (size_t)N_NODES * 4;
    unsigned short* h  = (unsigned short*)w;   w += (size_t)N_NODES * DOUT * 2;
    unsigned short* wb = (unsigned short*)w;
    float* out = (float*)d_out;                // [8192,256] fp32

    hipLaunchKernelGGL(convw_kernel,  dim3(256),  dim3(256), 0, stream, W1, wb);
    hipLaunchKernelGGL(gemm_h_kernel, dim3(512),  dim3(256), 0, stream,
                       x, wb, b1, a1w, a1b, a2w, a2b, h, g1, g2);
    hipLaunchKernelGGL(agg_kernel,    dim3(8192), dim3(256), 0, stream, adj, h, g1, g2, out);
}